// Round 17
// baseline (121.481 us; speedup 1.0000x reference)
//
#include <hip/hip_runtime.h>

typedef __attribute__((ext_vector_type(4))) float f32x4;
typedef __attribute__((ext_vector_type(8))) float f32x8;
typedef __attribute__((ext_vector_type(8))) unsigned short ushort8;
typedef __attribute__((ext_vector_type(4))) unsigned short ushort4v;
typedef __attribute__((ext_vector_type(8))) __bf16 bf16x8;

// 64^-0.05 * log2(e): folded into Q so softmax uses exp2 directly
#define QSCALE 1.17183256f

#if __has_builtin(__builtin_amdgcn_exp2f)
#define EXP2(x) __builtin_amdgcn_exp2f(x)
#else
#define EXP2(x) exp2f(x)
#endif

__device__ __forceinline__ unsigned short f2bf(float x) {
  unsigned u = __float_as_uint(x);
  u += 0x7FFFu + ((u >> 16) & 1u);
  return (unsigned short)(u >> 16);
}

__device__ __forceinline__ ushort8 cvt8(const float* src) {
  float4 x0 = *(const float4*)src;
  float4 x1 = *(const float4*)(src + 4);
  ushort8 v;
  v[0] = f2bf(x0.x); v[1] = f2bf(x0.y); v[2] = f2bf(x0.z); v[3] = f2bf(x0.w);
  v[4] = f2bf(x1.x); v[5] = f2bf(x1.y); v[6] = f2bf(x1.z); v[7] = f2bf(x1.w);
  return v;
}

__device__ __forceinline__ f32x4 mfma16(ushort8 a, ushort8 b, f32x4 c) {
  return __builtin_amdgcn_mfma_f32_16x16x32_bf16(
      __builtin_bit_cast(bf16x8, a), __builtin_bit_cast(bf16x8, b), c, 0, 0, 0);
}
__device__ __forceinline__ f32x4 mfma16b(bf16x8 a, ushort8 b, f32x4 c) {
  return __builtin_amdgcn_mfma_f32_16x16x32_bf16(
      a, __builtin_bit_cast(bf16x8, b), c, 0, 0, 0);
}

__device__ __forceinline__ void gload_lds16(const void* g, void* l) {
  __builtin_amdgcn_global_load_lds(
      (const __attribute__((address_space(1))) void*)g,
      (__attribute__((address_space(3))) void*)l, 16, 0, 0);
}

// ---------------- conversion pass: W matrices only (f32 -> bf16) ----------------
__global__ __launch_bounds__(256) void cvt_w_bf16(
    const float* __restrict__ s3, const float* __restrict__ s4, const float* __restrict__ s5,
    const float* __restrict__ s6, unsigned short* __restrict__ dstW)
{
  const int z = blockIdx.y;
  const float* src = (z == 0) ? s3 : (z == 1) ? s4 : (z == 2) ? s5 : s6;
  unsigned short* dst = dstW + (size_t)z * 1048576;
  int i = (blockIdx.x * 256 + threadIdx.x) * 8;
  const int stride = gridDim.x * 256 * 8;
  for (; i < 1048576; i += stride) *(ushort8*)(dst + i) = cvt8(src + i);
}

// ---------------- QKV GEMM: A staged f32 via gload_lds, W bf16; XCD swizzle -------
// A [128][32] f32 per buffer (16KB, chunk-swizzled c^(row&7)); W [128][32] bf16
// (4KB... 8KB). Fragment-read converts A via v_cvt_pk (compiler). LDS 48KB.
// z=0 -> Q (scaled, [B,H,S,D]); z=1 -> K; z=2 -> V^T ([B,H,D,S]).
__global__ __launch_bounds__(256) void gemm_qkv_bf(
    const float* __restrict__ Aq, const float* __restrict__ Ak, const float* __restrict__ Av,
    const unsigned short* __restrict__ Wbf,
    const float* __restrict__ bq, const float* __restrict__ bk, const float* __restrict__ bv,
    unsigned short* __restrict__ Qb, unsigned short* __restrict__ Kb,
    unsigned short* __restrict__ Vtb)
{
  // [Abuf0 16K][Abuf1 16K][Wbuf0 8K][Wbuf1 8K] = 48KB
  __shared__ __align__(16) char Sl[49152];
  const int lin = blockIdx.x + 8 * blockIdx.y + 256 * blockIdx.z;
  const int swz = (lin & 7) * 96 + (lin >> 3);
  const int bx = swz & 7, by = (swz >> 3) & 31, z = swz >> 8;

  const float* Af = (z == 0) ? Aq : (z == 1) ? Ak : Av;
  const unsigned short* Wp = Wbf + (size_t)z * 1048576;
  const float* bp = (z == 0) ? bq : (z == 1) ? bk : bv;

  const int t = threadIdx.x, l = t & 63, w = t >> 6;
  const int lr = l & 15, g = l >> 4;
  const int wm = (w >> 1) * 64, wn = (w & 1) * 64;

  // A staging: 1024 chunks (16B = 4 f32); p = j*256 + t; row = p>>3, chunk = p&7;
  // source k-chunk = (p&7) ^ (row&7)  (read side XORs the same way).
  int aprow[4], apch[4];
#pragma unroll
  for (int j = 0; j < 4; ++j) {
    int p = j * 256 + t;
    aprow[j] = p >> 3;
    apch[j] = (p & 7) ^ (aprow[j] & 7);
  }
  // W staging: 512 chunks; same geometry as before.
  int wprow[2], wpcol[2];
#pragma unroll
  for (int j = 0; j < 2; ++j) {
    int p = j * 256 + t;
    wprow[j] = p >> 2;
    wpcol[j] = (p & 3) ^ ((wprow[j] >> 1) & 3);
  }

  char* lds0 = &Sl[0];
  // A fragment byte offsets (f32): row = wm + m*16 + lr; row&7 == lr&7.
  const int abase = (wm + lr) * 128;
  const int aoff0 = abase + (((2 * g) ^ (lr & 7)) << 4);
  const int aoff1 = abase + (((2 * g + 1) ^ (lr & 7)) << 4);
  // W fragment byte offsets (bf16): as R14.
  const int brow0 = wn + lr;
  const int bbyte = (brow0 * 32 + (g ^ ((brow0 >> 1) & 3)) * 8) * 2;

  f32x4 acc[4][4] = {};

#define STAGE_QKV(aoffb, woffb, k0)                                               \
  {                                                                               \
    _Pragma("unroll") for (int j = 0; j < 4; ++j)                                 \
      gload_lds16(Af + (size_t)(by * 128 + aprow[j]) * 1024 + (k0) + apch[j] * 4, \
                  lds0 + (aoffb) + (j * 256 + w * 64) * 16);                      \
    _Pragma("unroll") for (int j = 0; j < 2; ++j)                                 \
      gload_lds16(Wp + (size_t)(bx * 128 + wprow[j]) * 1024 + (k0) + wpcol[j] * 8,\
                  lds0 + (woffb) + (j * 256 + w * 64) * 16);                      \
  }

  STAGE_QKV(0, 32768, 0)
  __syncthreads();

  for (int kt = 0; kt < 32; ++kt) {
    const int aoffc = (kt & 1) << 14;
    const int woffc = 32768 + ((kt & 1) << 13);
    if (kt < 31) STAGE_QKV(aoffc ^ 16384, woffc ^ 8192, (kt + 1) * 32)
    const char* pa = lds0 + aoffc;
    const char* pw = lds0 + woffc;
    bf16x8 af[4];
    ushort8 b[4];
#pragma unroll
    for (int m = 0; m < 4; ++m) {
      f32x4 lo = *(const f32x4*)(pa + aoff0 + m * 2048);
      f32x4 hi = *(const f32x4*)(pa + aoff1 + m * 2048);
      f32x8 v = {lo[0], lo[1], lo[2], lo[3], hi[0], hi[1], hi[2], hi[3]};
      af[m] = __builtin_convertvector(v, bf16x8);
    }
#pragma unroll
    for (int n = 0; n < 4; ++n)
      b[n] = *(const ushort8*)(pw + bbyte + n * 1024);
#pragma unroll
    for (int m = 0; m < 4; ++m)
#pragma unroll
      for (int n = 0; n < 4; ++n)
        acc[m][n] = mfma16b(af[m], b[n], acc[m][n]);
    __syncthreads();
  }

  float bias_n[4];
#pragma unroll
  for (int n = 0; n < 4; ++n) bias_n[n] = bp[bx * 128 + wn + n * 16 + lr];

  if (z < 2) {
    const float sc = (z == 0) ? QSCALE : 1.0f;
    unsigned short* Cp = z ? Kb : Qb;
#pragma unroll
    for (int m = 0; m < 4; ++m)
#pragma unroll
      for (int n = 0; n < 4; ++n)
#pragma unroll
        for (int r = 0; r < 4; ++r) {
          float v = (acc[m][n][r] + bias_n[n]) * sc;
          int gm = by * 128 + wm + m * 16 + g * 4 + r;
          int gn = bx * 128 + wn + n * 16 + lr;
          int bb = gm >> 11, s = gm & 2047;
          int h = gn >> 6, d = gn & 63;
          Cp[((size_t)((bb * 16 + h) * 2048 + s) << 6) + d] = f2bf(v);
        }
  } else {
#pragma unroll
    for (int m = 0; m < 4; ++m) {
      int gm0 = by * 128 + wm + m * 16 + g * 4;
      int bb = gm0 >> 11, s0 = gm0 & 2047;
#pragma unroll
      for (int n = 0; n < 4; ++n) {
        int gn = bx * 128 + wn + n * 16 + lr;
        int h = gn >> 6, d = gn & 63;
        ushort4v pk;
#pragma unroll
        for (int r = 0; r < 4; ++r) pk[r] = f2bf(acc[m][n][r] + bias_n[n]);
        *(ushort4v*)&Vtb[((size_t)((bb * 16 + h) * 64 + d) << 11) + s0] = pk;
      }
    }
  }
}

// ---------------- bf16 output projection, tile 128x64, XCD swizzle ----------------
__global__ __launch_bounds__(256) void gemm_o_bf(
    const unsigned short* __restrict__ AO, const unsigned short* __restrict__ Wp,
    const float* __restrict__ bo, float* __restrict__ C)
{
  __shared__ __align__(16) unsigned short Al[2][128 * 32];
  __shared__ __align__(16) unsigned short Wl[2][64 * 32];
  const int lin = blockIdx.x + 16 * blockIdx.y;
  const int swz = (lin & 7) * 64 + (lin >> 3);
  const int bx = swz & 15, by = swz >> 4;

  const int t = threadIdx.x, l = t & 63, w = t >> 6;
  const int lr = l & 15, g = l >> 4;
  const int wm = w * 32;

  int prow[2], pcol[2];
#pragma unroll
  for (int j = 0; j < 2; ++j) {
    int p = j * 256 + w * 64 + l;
    prow[j] = p >> 2;
    pcol[j] = (p & 3) ^ ((prow[j] >> 1) & 3);
  }

  f32x4 acc[2][4] = {};

#define STAGE_O(buf, k0)                                                          \
  {                                                                               \
    _Pragma("unroll") for (int j = 0; j < 2; ++j) {                               \
      gload_lds16(AO + (size_t)(by * 128 + prow[j]) * 1024 + (k0) + pcol[j] * 8,  \
                  &Al[buf][(j * 256 + w * 64) * 8]);                              \
    }                                                                             \
    gload_lds16(Wp + (size_t)(bx * 64 + prow[0]) * 1024 + (k0) + pcol[0] * 8,     \
                &Wl[buf][(w * 64) * 8]);                                          \
  }

  STAGE_O(0, 0)
  __syncthreads();

  for (int kt = 0; kt < 32; ++kt) {
    const int cur = kt & 1;
    if (kt < 31) STAGE_O(cur ^ 1, (kt + 1) * 32)
    ushort8 a[2], b[4];
#pragma unroll
    for (int m = 0; m < 2; ++m) {
      int r = wm + m * 16 + lr;
      a[m] = *(const ushort8*)&Al[cur][r * 32 + (g ^ ((r >> 1) & 3)) * 8];
    }
#pragma unroll
    for (int n = 0; n < 4; ++n) {
      int r = n * 16 + lr;
      b[n] = *(const ushort8*)&Wl[cur][r * 32 + (g ^ ((r >> 1) & 3)) * 8];
    }
#pragma unroll
    for (int m = 0; m < 2; ++m)
#pragma unroll
      for (int n = 0; n < 4; ++n)
        acc[m][n] = mfma16(a[m], b[n], acc[m][n]);
    __syncthreads();
  }

  float bias_n[4];
#pragma unroll
  for (int n = 0; n < 4; ++n) bias_n[n] = bo[bx * 64 + n * 16 + lr];

#pragma unroll
  for (int m = 0; m < 2; ++m)
#pragma unroll
    for (int n = 0; n < 4; ++n)
#pragma unroll
      for (int r = 0; r < 4; ++r) {
        int gm = by * 128 + wm + m * 16 + g * 4 + r;
        int gn = bx * 64 + n * 16 + lr;
        C[(size_t)gm * 1024 + gn] = acc[m][n][r] + bias_n[n];
      }
}

// ---------------- flash attention: split-k waves (R16-exact) ----------------
__global__ __launch_bounds__(512) void attn_fwd(
    const unsigned short* __restrict__ Qb, const unsigned short* __restrict__ Kb,
    const unsigned short* __restrict__ Vtb, unsigned short* __restrict__ AO)
{
  __shared__ __align__(16) unsigned short Kl[4][64 * 64];
  __shared__ __align__(16) unsigned short Vl[4][64 * 64];
  const int t = threadIdx.x;
  const int l = t & 63, w = t >> 6;
  const int lr = l & 15, g = l >> 4;
  const int wq = w & 3, kh = w >> 2;
  const int lin = blockIdx.x + 16 * blockIdx.y;
  const int swz = (lin & 7) * 64 + (lin >> 3);
  const int qt = swz & 15, bh = swz >> 4;

  const unsigned short* Qh = Qb + (size_t)bh * (2048 * 64);
  const unsigned short* Kh = Kb + (size_t)bh * (2048 * 64);
  const unsigned short* Vth = Vtb + (size_t)bh * (64 * 2048);

  ushort8 aq[2][2];
#pragma unroll
  for (int m = 0; m < 2; ++m)
#pragma unroll
    for (int kk = 0; kk < 2; ++kk) {
      int q = qt * 128 + wq * 32 + m * 16 + lr;
      aq[m][kk] = *(const ushort8*)&Qh[q * 64 + kk * 32 + g * 8];
    }

  ushort8 ones;
#pragma unroll
  for (int j = 0; j < 8; ++j) ones[j] = 0x3F80;

  f32x4 o[2][4] = {};
  f32x4 lacc[2] = {};

  const int sr = t >> 3, sc = t & 7;
  ushort8 rk, rv;

#define STAGE_ATTN(buf)                                                      \
  {                                                                          \
    *(ushort8*)&Kl[buf][sr * 64 + ((sc ^ (sr & 7))) * 8] = rk;               \
    _Pragma("unroll") for (int h = 0; h < 2; ++h) {                          \
      int tw = 2 * sc + h;                                                   \
      int n4 = tw >> 2, gg = tw & 3;                                         \
      int chunk = ((n4 >> 1) << 2) + gg;                                     \
      int within = (n4 & 1) << 2;                                            \
      ushort4v hv = h ? __builtin_shufflevector(rv, rv, 4, 5, 6, 7)          \
                      : __builtin_shufflevector(rv, rv, 0, 1, 2, 3);         \
      *(ushort4v*)&Vl[buf][sr * 64 + ((chunk ^ (sr & 7))) * 8 + within] = hv;\
    }                                                                        \
  }

#define LOAD_NEXT(tile)                                                      \
  {                                                                          \
    rk = *(const ushort8*)&Kh[((tile) * 64 + sr) * 64 + sc * 8];             \
    rv = *(const ushort8*)&Vth[sr * 2048 + (tile) * 64 + sc * 8];            \
  }

#define COMPUTE_ATTN(cur)                                                    \
  {                                                                          \
    f32x4 s[2][2] = {};                                                      \
    __builtin_amdgcn_s_setprio(1);                                           \
    _Pragma("unroll") for (int kk = 0; kk < 2; ++kk) {                       \
      _Pragma("unroll") for (int n = 0; n < 2; ++n) {                        \
        ushort8 ak = *(const ushort8*)&Kl[cur][(kh * 32 + n * 16 + lr) * 64 +\
                                              (((kk * 4 + g) ^ (lr & 7))) * 8]; \
        _Pragma("unroll") for (int m = 0; m < 2; ++m)                        \
          s[n][m] = mfma16(ak, aq[m][kk], s[n][m]);                          \
      }                                                                      \
    }                                                                        \
    __builtin_amdgcn_s_setprio(0);                                           \
    float p[2][2][4];                                                        \
    _Pragma("unroll") for (int n = 0; n < 2; ++n)                            \
      _Pragma("unroll") for (int m = 0; m < 2; ++m)                          \
        _Pragma("unroll") for (int r = 0; r < 4; ++r)                        \
          p[n][m][r] = EXP2(s[n][m][r]);                                     \
    bf16x8 pa[2];                                                            \
    _Pragma("unroll") for (int m = 0; m < 2; ++m) {                          \
      f32x8 v = {p[0][m][0], p[0][m][1], p[0][m][2], p[0][m][3],             \
                 p[1][m][0], p[1][m][1], p[1][m][2], p[1][m][3]};            \
      pa[m] = __builtin_convertvector(v, bf16x8);                            \
    }                                                                        \
    __builtin_amdgcn_s_setprio(1);                                           \
    _Pragma("unroll") for (int m = 0; m < 2; ++m)                            \
      lacc[m] = mfma16b(pa[m], ones, lacc[m]);                               \
    _Pragma("unroll") for (int n = 0; n < 4; ++n) {                          \
      int d = n * 16 + lr;                                                   \
      ushort8 bv = *(const ushort8*)&Vl[cur][d * 64 +                        \
                                            (((kh * 4 + g) ^ (d & 7))) * 8]; \
      _Pragma("unroll") for (int m = 0; m < 2; ++m)                          \
        o[m][n] = mfma16b(pa[m], bv, o[m][n]);                               \
    }                                                                        \
    __builtin_amdgcn_s_setprio(0);                                           \
  }

  LOAD_NEXT(0)
  STAGE_ATTN(0)
  LOAD_NEXT(1)
  STAGE_ATTN(1)
  __syncthreads();

  for (int jj = 0; jj < 8; ++jj) {
    LOAD_NEXT(4 * jj + 2)
    COMPUTE_ATTN(0)
    STAGE_ATTN(2)
    LOAD_NEXT(4 * jj + 3)
    COMPUTE_ATTN(1)
    STAGE_ATTN(3)
    __syncthreads();
    if (jj < 7) LOAD_NEXT(4 * jj + 4)
    COMPUTE_ATTN(2)
    if (jj < 7) STAGE_ATTN(0)
    if (jj < 7) LOAD_NEXT(4 * jj + 5)
    COMPUTE_ATTN(3)
    if (jj < 7) STAGE_ATTN(1)
    __syncthreads();
  }

  __syncthreads();
  float* Of = (float*)&Kl[0][0];
  if (kh == 1) {
#pragma unroll
    for (int m = 0; m < 2; ++m)
#pragma unroll
      for (int n = 0; n < 4; ++n)
#pragma unroll
        for (int r = 0; r < 4; ++r)
          Of[(wq * 32 + m * 16 + g * 4 + r) * 64 + n * 16 + lr] = o[m][n][r];
  }
  __syncthreads();
  if (kh == 0) {
#pragma unroll
    for (int m = 0; m < 2; ++m)
#pragma unroll
      for (int n = 0; n < 4; ++n)
#pragma unroll
        for (int r = 0; r < 4; ++r)
          o[m][n][r] += Of[(wq * 32 + m * 16 + g * 4 + r) * 64 + n * 16 + lr];
  }
  __syncthreads();
  float* Lf = (float*)&Kl[0][0];
  if (kh == 1 && lr == 0) {
#pragma unroll
    for (int m = 0; m < 2; ++m)
#pragma unroll
      for (int r = 0; r < 4; ++r)
        Lf[wq * 32 + m * 16 + g * 4 + r] = lacc[m][r];
  }
  __syncthreads();
  if (kh == 0) {
    const int bb = bh >> 4, h = bh & 15;
#pragma unroll
    for (int m = 0; m < 2; ++m) {
      float inv[4];
#pragma unroll
      for (int r = 0; r < 4; ++r)
        inv[r] = 1.0f / (lacc[m][r] + Lf[wq * 32 + m * 16 + g * 4 + r]);
#pragma unroll
      for (int n = 0; n < 4; ++n)
#pragma unroll
        for (int r = 0; r < 4; ++r) {
          int q = qt * 128 + wq * 32 + m * 16 + g * 4 + r;
          AO[(size_t)(bb * 2048 + q) * 1024 + h * 64 + n * 16 + lr] =
              f2bf(o[m][n][r] * inv[r]);
        }
    }
  }
}

// ---------------- fallback kernels (small workspace) ----------------
__global__ __launch_bounds__(256) void gemm_qkv_f32(
    const float* __restrict__ Aq, const float* __restrict__ Ak, const float* __restrict__ Av,
    const float* __restrict__ Wq, const float* __restrict__ Wk, const float* __restrict__ Wv,
    const float* __restrict__ bq, const float* __restrict__ bk, const float* __restrict__ bv,
    unsigned short* __restrict__ Qb, unsigned short* __restrict__ Kb, unsigned short* __restrict__ Vtb)
{
  __shared__ __align__(16) unsigned short Al[128 * 32];
  __shared__ __align__(16) unsigned short Wl[128 * 32];
  const int z = blockIdx.z;
  const float* Ap = (z == 0) ? Aq : (z == 1) ? Ak : Av;
  const float* Wp = (z == 0) ? Wq : (z == 1) ? Wk : Wv;
  const float* bp = (z == 0) ? bq : (z == 1) ? bk : bv;

  const int t = threadIdx.x;
  const int l = t & 63, w = t >> 6;
  const int lr = l & 15, g = l >> 4;
  const int wm = (w >> 1) * 64, wn = (w & 1) * 64;
  const int bx = blockIdx.x, by = blockIdx.y;
  const int r0 = t >> 2, c0 = t & 3;

  f32x4 acc[4][4] = {};

  for (int k0 = 0; k0 < 1024; k0 += 32) {
    __syncthreads();
#pragma unroll
    for (int i = 0; i < 2; ++i) {
      int r = r0 + i * 64;
      int cs = c0 ^ ((r >> 1) & 3);
      *(ushort8*)&Al[r * 32 + cs * 8] = cvt8(Ap + (size_t)(by * 128 + r) * 1024 + k0 + c0 * 8);
      *(ushort8*)&Wl[r * 32 + cs * 8] = cvt8(Wp + (size_t)(bx * 128 + r) * 1024 + k0 + c0 * 8);
    }
    __syncthreads();
    ushort8 a[4], b[4];
#pragma unroll
    for (int m = 0; m < 4; ++m) {
      int r = wm + m * 16 + lr;
      a[m] = *(const ushort8*)&Al[r * 32 + (g ^ ((r >> 1) & 3)) * 8];
    }
#pragma unroll
    for (int n = 0; n < 4; ++n) {
      int r = wn + n * 16 + lr;
      b[n] = *(const ushort8*)&Wl[r * 32 + (g ^ ((r >> 1) & 3)) * 8];
    }
#pragma unroll
    for (int m = 0; m < 4; ++m)
#pragma unroll
      for (int n = 0; n < 4; ++n)
        acc[m][n] = mfma16(a[m], b[n], acc[m][n]);
  }

  float bias_n[4];
#pragma unroll
  for (int n = 0; n < 4; ++n) bias_n[n] = bp[bx * 128 + wn + n * 16 + lr];

  if (z < 2) {
    const float sc = (z == 0) ? QSCALE : 1.0f;
    unsigned short* Cp = z ? Kb : Qb;
#pragma unroll
    for (int m = 0; m < 4; ++m)
#pragma unroll
      for (int n = 0; n < 4; ++n)
#pragma unroll
        for (int r = 0; r < 4; ++r) {
          float v = (acc[m][n][r] + bias_n[n]) * sc;
          int gm = by * 128 + wm + m * 16 + g * 4 + r;
          int gn = bx * 128 + wn + n * 16 + lr;
          int bb = gm >> 11, s = gm & 2047;
          int h = gn >> 6, d = gn & 63;
          Cp[((size_t)((bb * 16 + h) * 2048 + s) << 6) + d] = f2bf(v);
        }
  } else {
#pragma unroll
    for (int m = 0; m < 4; ++m) {
      int gm0 = by * 128 + wm + m * 16 + g * 4;
      int bb = gm0 >> 11, s0 = gm0 & 2047;
#pragma unroll
      for (int n = 0; n < 4; ++n) {
        int gn = bx * 128 + wn + n * 16 + lr;
        int h = gn >> 6, d = gn & 63;
        ushort4v pk;
#pragma unroll
        for (int r = 0; r < 4; ++r) pk[r] = f2bf(acc[m][n][r] + bias_n[n]);
        *(ushort4v*)&Vtb[((size_t)((bb * 16 + h) * 64 + d) << 11) + s0] = pk;
      }
    }
  }
}

__global__ __launch_bounds__(256) void gemm_o_f32(
    const unsigned short* __restrict__ AO, const float* __restrict__ Wo,
    const float* __restrict__ bo, float* __restrict__ C)
{
  __shared__ __align__(16) unsigned short Al[128 * 32];
  __shared__ __align__(16) unsigned short Wl[64 * 32];
  const int t = threadIdx.x;
  const int l = t & 63, w = t >> 6;
  const int lr = l & 15, g = l >> 4;
  const int wm = w * 32;
  const int bx = blockIdx.x, by = blockIdx.y;
  const int r0 = t >> 2, c0 = t & 3;

  f32x4 acc[2][4] = {};

  for (int k0 = 0; k0 < 1024; k0 += 32) {
    __syncthreads();
#pragma unroll
    for (int i = 0; i < 2; ++i) {
      int r = r0 + i * 64;
      int cs = c0 ^ ((r >> 1) & 3);
      *(ushort8*)&Al[r * 32 + cs * 8] =
          *(const ushort8*)&AO[(size_t)(by * 128 + r) * 1024 + k0 + c0 * 8];
    }
    {
      int r = r0;
      int cs = c0 ^ ((r >> 1) & 3);
      *(ushort8*)&Wl[r * 32 + cs * 8] = cvt8(Wo + (size_t)(bx * 64 + r) * 1024 + k0 + c0 * 8);
    }
    __syncthreads();
    ushort8 a[2], b[4];
#pragma unroll
    for (int m = 0; m < 2; ++m) {
      int r = wm + m * 16 + lr;
      a[m] = *(const ushort8*)&Al[r * 32 + (g ^ ((r >> 1) & 3)) * 8];
    }
#pragma unroll
    for (int n = 0; n < 4; ++n) {
      int r = n * 16 + lr;
      b[n] = *(const ushort8*)&Wl[r * 32 + (g ^ ((r >> 1) & 3)) * 8];
    }
#pragma unroll
    for (int m = 0; m < 2; ++m)
#pragma unroll
      for (int n = 0; n < 4; ++n)
        acc[m][n] = mfma16(a[m], b[n], acc[m][n]);
  }

  float bias_n[4];
#pragma unroll
  for (int n = 0; n < 4; ++n) bias_n[n] = bo[bx * 64 + n * 16 + lr];

#pragma unroll
  for (int m = 0; m < 2; ++m)
#pragma unroll
    for (int n = 0; n < 4; ++n)
#pragma unroll
      for (int r = 0; r < 4; ++r) {
        int gm = by * 128 + wm + m * 16 + g * 4 + r;
        int gn = bx * 64 + n * 16 + lr;
        C[(size_t)gm * 1024 + gn] = acc[m][n][r] + bias_n[n];
      }
}

extern "C" void kernel_launch(void* const* d_in, const int* in_sizes, int n_in,
                              void* d_out, int out_size, void* d_ws, size_t ws_size,
                              hipStream_t stream) {
  (void)in_sizes; (void)n_in; (void)out_size;
  const float* querys = (const float*)d_in[0];
  const float* keys   = (const float*)d_in[1];
  const float* values = (const float*)d_in[2];
  const float* Wq = (const float*)d_in[3];
  const float* bq = (const float*)d_in[4];
  const float* Wk = (const float*)d_in[5];
  const float* bk = (const float*)d_in[6];
  const float* Wv = (const float*)d_in[7];
  const float* bv = (const float*)d_in[8];
  const float* Wo = (const float*)d_in[9];
  const float* bo = (const float*)d_in[10];

  const size_t need = (size_t)29360128 * 2;  // 58.7 MB (same guard as before)
  if (ws_size >= need) {
    // layout (ushort units): Wbf[4M] | Qb[4M] | Kb[4M] | Vtb[4M] | AO[4M] = 40MB
    unsigned short* Wbf = (unsigned short*)d_ws;
    unsigned short* Qb  = Wbf + 4194304;
    unsigned short* Kb  = Qb + 4194304;
    unsigned short* Vtb = Kb + 4194304;
    unsigned short* AO  = Vtb + 4194304;

    cvt_w_bf16<<<dim3(512, 4), 256, 0, stream>>>(Wq, Wk, Wv, Wo, Wbf);
    gemm_qkv_bf<<<dim3(8, 32, 3), 256, 0, stream>>>(querys, keys, values, Wbf,
                                                    bq, bk, bv, Qb, Kb, Vtb);
    attn_fwd<<<dim3(16, 32), 512, 0, stream>>>(Qb, Kb, Vtb, AO);
    gemm_o_bf<<<dim3(16, 32), 256, 0, stream>>>(AO, Wbf + 3 * 1048576, bo, (float*)d_out);
  } else {
    unsigned short* Qb  = (unsigned short*)d_ws;
    unsigned short* Kb  = Qb + (size_t)4194304;
    unsigned short* Vtb = Kb + (size_t)4194304;
    unsigned short* AO  = Vtb + (size_t)4194304;

    gemm_qkv_f32<<<dim3(8, 32, 3), 256, 0, stream>>>(querys, keys, values, Wq, Wk, Wv,
                                                     bq, bk, bv, Qb, Kb, Vtb);
    attn_fwd<<<dim3(16, 32), 512, 0, stream>>>(Qb, Kb, Vtb, AO);
    gemm_o_f32<<<dim3(16, 32), 256, 0, stream>>>(AO, Wo, bo, (float*)d_out);
  }
}

// Round 18
// 120.237 us; speedup vs baseline: 1.0103x; 1.0103x over previous
//
#include <hip/hip_runtime.h>

typedef __attribute__((ext_vector_type(4))) float f32x4;
typedef __attribute__((ext_vector_type(8))) float f32x8;
typedef __attribute__((ext_vector_type(8))) unsigned short ushort8;
typedef __attribute__((ext_vector_type(4))) unsigned short ushort4v;
typedef __attribute__((ext_vector_type(8))) __bf16 bf16x8;

// 64^-0.05 * log2(e): folded into Q so softmax uses exp2 directly
#define QSCALE 1.17183256f

#if __has_builtin(__builtin_amdgcn_exp2f)
#define EXP2(x) __builtin_amdgcn_exp2f(x)
#else
#define EXP2(x) exp2f(x)
#endif

__device__ __forceinline__ unsigned short f2bf(float x) {
  unsigned u = __float_as_uint(x);
  u += 0x7FFFu + ((u >> 16) & 1u);
  return (unsigned short)(u >> 16);
}

__device__ __forceinline__ ushort8 cvt8(const float* src) {
  float4 x0 = *(const float4*)src;
  float4 x1 = *(const float4*)(src + 4);
  ushort8 v;
  v[0] = f2bf(x0.x); v[1] = f2bf(x0.y); v[2] = f2bf(x0.z); v[3] = f2bf(x0.w);
  v[4] = f2bf(x1.x); v[5] = f2bf(x1.y); v[6] = f2bf(x1.z); v[7] = f2bf(x1.w);
  return v;
}

__device__ __forceinline__ f32x4 mfma16(ushort8 a, ushort8 b, f32x4 c) {
  return __builtin_amdgcn_mfma_f32_16x16x32_bf16(
      __builtin_bit_cast(bf16x8, a), __builtin_bit_cast(bf16x8, b), c, 0, 0, 0);
}
__device__ __forceinline__ f32x4 mfma16b(bf16x8 a, ushort8 b, f32x4 c) {
  return __builtin_amdgcn_mfma_f32_16x16x32_bf16(
      a, __builtin_bit_cast(bf16x8, b), c, 0, 0, 0);
}

__device__ __forceinline__ void gload_lds16(const void* g, void* l) {
  __builtin_amdgcn_global_load_lds(
      (const __attribute__((address_space(1))) void*)g,
      (__attribute__((address_space(3))) void*)l, 16, 0, 0);
}

// ---------------- conversion pass: f32 -> bf16, one shot ----------------
__global__ __launch_bounds__(256) void cvt_f32_bf16(
    const float* __restrict__ s0, const float* __restrict__ s1, const float* __restrict__ s2,
    const float* __restrict__ s3, const float* __restrict__ s4, const float* __restrict__ s5,
    const float* __restrict__ s6, unsigned short* __restrict__ dstA,
    unsigned short* __restrict__ dstW)
{
  const int z = blockIdx.y;
  const float* src;
  unsigned short* dst;
  int n;
  if (z < 3) {
    src = (z == 0) ? s0 : (z == 1) ? s1 : s2;
    dst = dstA + (size_t)z * 4194304;
    n = 4194304;
  } else {
    src = (z == 3) ? s3 : (z == 4) ? s4 : (z == 5) ? s5 : s6;
    dst = dstW + (size_t)(z - 3) * 1048576;
    n = 1048576;
  }
  int i = (blockIdx.x * 256 + threadIdx.x) * 8;
  const int stride = gridDim.x * 256 * 8;
  for (; i < n; i += stride) *(ushort8*)(dst + i) = cvt8(src + i);
}

// ---------------- bf16 QKV GEMM, 128x128, 2-buffer gload_lds, XCD swizzle ---------
// R14-exact: combined LDS block, strength-reduced fragment addresses.
__global__ __launch_bounds__(256) void gemm_qkv_bf(
    const unsigned short* __restrict__ Abf, const unsigned short* __restrict__ Wbf,
    const float* __restrict__ bq, const float* __restrict__ bk, const float* __restrict__ bv,
    unsigned short* __restrict__ Qb, unsigned short* __restrict__ Kb,
    unsigned short* __restrict__ Vtb)
{
  __shared__ __align__(16) unsigned short Sl[4][4096];
  const int lin = blockIdx.x + 8 * blockIdx.y + 256 * blockIdx.z;
  const int swz = (lin & 7) * 96 + (lin >> 3);
  const int bx = swz & 7, by = (swz >> 3) & 31, z = swz >> 8;

  const unsigned short* Ap = Abf + (size_t)z * 4194304;
  const unsigned short* Wp = Wbf + (size_t)z * 1048576;
  const float* bp = (z == 0) ? bq : (z == 1) ? bk : bv;

  const int t = threadIdx.x, l = t & 63, w = t >> 6;
  const int lr = l & 15, g = l >> 4;
  const int wm = (w >> 1) * 64, wn = (w & 1) * 64;

  int prow[2], pcol[2];
#pragma unroll
  for (int j = 0; j < 2; ++j) {
    int p = j * 256 + w * 64 + l;
    prow[j] = p >> 2;
    pcol[j] = (p & 3) ^ ((prow[j] >> 1) & 3);
  }

  char* lds0 = (char*)&Sl[0][0];
  const int arow0 = wm + lr, brow0 = wn + lr;
  const int abyte = (arow0 * 32 + (g ^ ((arow0 >> 1) & 3)) * 8) * 2;
  const int bbyte = 8192 + (brow0 * 32 + (g ^ ((brow0 >> 1) & 3)) * 8) * 2;

  f32x4 acc[4][4] = {};

#define STAGE_QKV(bufoff, k0)                                                     \
  {                                                                               \
    _Pragma("unroll") for (int j = 0; j < 2; ++j) {                               \
      gload_lds16(Ap + (size_t)(by * 128 + prow[j]) * 1024 + (k0) + pcol[j] * 8,  \
                  lds0 + (bufoff) + (j * 256 + w * 64) * 16);                     \
      gload_lds16(Wp + (size_t)(bx * 128 + prow[j]) * 1024 + (k0) + pcol[j] * 8,  \
                  lds0 + (bufoff) + 8192 + (j * 256 + w * 64) * 16);              \
    }                                                                             \
  }

  STAGE_QKV(0, 0)
  __syncthreads();

  for (int kt = 0; kt < 32; ++kt) {
    const int curoff = (kt & 1) << 14;
    if (kt < 31) STAGE_QKV(curoff ^ 16384, (kt + 1) * 32)
    const char* pa = lds0 + curoff;
    ushort8 a[4], b[4];
#pragma unroll
    for (int m = 0; m < 4; ++m)
      a[m] = *(const ushort8*)(pa + abyte + m * 1024);
#pragma unroll
    for (int n = 0; n < 4; ++n)
      b[n] = *(const ushort8*)(pa + bbyte + n * 1024);
#pragma unroll
    for (int m = 0; m < 4; ++m)
#pragma unroll
      for (int n = 0; n < 4; ++n)
        acc[m][n] = mfma16(a[m], b[n], acc[m][n]);
    __syncthreads();
  }

  float bias_n[4];
#pragma unroll
  for (int n = 0; n < 4; ++n) bias_n[n] = bp[bx * 128 + wn + n * 16 + lr];

  if (z < 2) {
    const float sc = (z == 0) ? QSCALE : 1.0f;
    unsigned short* Cp = z ? Kb : Qb;
#pragma unroll
    for (int m = 0; m < 4; ++m)
#pragma unroll
      for (int n = 0; n < 4; ++n)
#pragma unroll
        for (int r = 0; r < 4; ++r) {
          float v = (acc[m][n][r] + bias_n[n]) * sc;
          int gm = by * 128 + wm + m * 16 + g * 4 + r;
          int gn = bx * 128 + wn + n * 16 + lr;
          int bb = gm >> 11, s = gm & 2047;
          int h = gn >> 6, d = gn & 63;
          Cp[((size_t)((bb * 16 + h) * 2048 + s) << 6) + d] = f2bf(v);
        }
  } else {
#pragma unroll
    for (int m = 0; m < 4; ++m) {
      int gm0 = by * 128 + wm + m * 16 + g * 4;
      int bb = gm0 >> 11, s0 = gm0 & 2047;
#pragma unroll
      for (int n = 0; n < 4; ++n) {
        int gn = bx * 128 + wn + n * 16 + lr;
        int h = gn >> 6, d = gn & 63;
        ushort4v pk;
#pragma unroll
        for (int r = 0; r < 4; ++r) pk[r] = f2bf(acc[m][n][r] + bias_n[n]);
        *(ushort4v*)&Vtb[((size_t)((bb * 16 + h) * 64 + d) << 11) + s0] = pk;
      }
    }
  }
}

// ---------------- bf16 output projection, tile 128x64, XCD swizzle ----------------
__global__ __launch_bounds__(256) void gemm_o_bf(
    const unsigned short* __restrict__ AO, const unsigned short* __restrict__ Wp,
    const float* __restrict__ bo, float* __restrict__ C)
{
  __shared__ __align__(16) unsigned short Al[2][128 * 32];
  __shared__ __align__(16) unsigned short Wl[2][64 * 32];
  const int lin = blockIdx.x + 16 * blockIdx.y;
  const int swz = (lin & 7) * 64 + (lin >> 3);
  const int bx = swz & 15, by = swz >> 4;

  const int t = threadIdx.x, l = t & 63, w = t >> 6;
  const int lr = l & 15, g = l >> 4;
  const int wm = w * 32;

  int prow[2], pcol[2];
#pragma unroll
  for (int j = 0; j < 2; ++j) {
    int p = j * 256 + w * 64 + l;
    prow[j] = p >> 2;
    pcol[j] = (p & 3) ^ ((prow[j] >> 1) & 3);
  }

  f32x4 acc[2][4] = {};

#define STAGE_O(buf, k0)                                                          \
  {                                                                               \
    _Pragma("unroll") for (int j = 0; j < 2; ++j) {                               \
      gload_lds16(AO + (size_t)(by * 128 + prow[j]) * 1024 + (k0) + pcol[j] * 8,  \
                  &Al[buf][(j * 256 + w * 64) * 8]);                              \
    }                                                                             \
    gload_lds16(Wp + (size_t)(bx * 64 + prow[0]) * 1024 + (k0) + pcol[0] * 8,     \
                &Wl[buf][(w * 64) * 8]);                                          \
  }

  STAGE_O(0, 0)
  __syncthreads();

  for (int kt = 0; kt < 32; ++kt) {
    const int cur = kt & 1;
    if (kt < 31) STAGE_O(cur ^ 1, (kt + 1) * 32)
    ushort8 a[2], b[4];
#pragma unroll
    for (int m = 0; m < 2; ++m) {
      int r = wm + m * 16 + lr;
      a[m] = *(const ushort8*)&Al[cur][r * 32 + (g ^ ((r >> 1) & 3)) * 8];
    }
#pragma unroll
    for (int n = 0; n < 4; ++n) {
      int r = n * 16 + lr;
      b[n] = *(const ushort8*)&Wl[cur][r * 32 + (g ^ ((r >> 1) & 3)) * 8];
    }
#pragma unroll
    for (int m = 0; m < 2; ++m)
#pragma unroll
      for (int n = 0; n < 4; ++n)
        acc[m][n] = mfma16(a[m], b[n], acc[m][n]);
    __syncthreads();
  }

  float bias_n[4];
#pragma unroll
  for (int n = 0; n < 4; ++n) bias_n[n] = bo[bx * 64 + n * 16 + lr];

#pragma unroll
  for (int m = 0; m < 2; ++m)
#pragma unroll
    for (int n = 0; n < 4; ++n)
#pragma unroll
      for (int r = 0; r < 4; ++r) {
        int gm = by * 128 + wm + m * 16 + g * 4 + r;
        int gn = bx * 64 + n * 16 + lr;
        C[(size_t)gm * 1024 + gn] = acc[m][n][r] + bias_n[n];
      }
}

// ---------------- flash attention: split-k waves (4 q-groups x 2 k-halves) ---------
__global__ __launch_bounds__(512) void attn_fwd(
    const unsigned short* __restrict__ Qb, const unsigned short* __restrict__ Kb,
    const unsigned short* __restrict__ Vtb, unsigned short* __restrict__ AO)
{
  __shared__ __align__(16) unsigned short Kl[4][64 * 64];
  __shared__ __align__(16) unsigned short Vl[4][64 * 64];
  const int t = threadIdx.x;
  const int l = t & 63, w = t >> 6;
  const int lr = l & 15, g = l >> 4;
  const int wq = w & 3, kh = w >> 2;
  const int lin = blockIdx.x + 16 * blockIdx.y;
  const int swz = (lin & 7) * 64 + (lin >> 3);
  const int qt = swz & 15, bh = swz >> 4;

  const unsigned short* Qh = Qb + (size_t)bh * (2048 * 64);
  const unsigned short* Kh = Kb + (size_t)bh * (2048 * 64);
  const unsigned short* Vth = Vtb + (size_t)bh * (64 * 2048);

  ushort8 aq[2][2];
#pragma unroll
  for (int m = 0; m < 2; ++m)
#pragma unroll
    for (int kk = 0; kk < 2; ++kk) {
      int q = qt * 128 + wq * 32 + m * 16 + lr;
      aq[m][kk] = *(const ushort8*)&Qh[q * 64 + kk * 32 + g * 8];
    }

  ushort8 ones;
#pragma unroll
  for (int j = 0; j < 8; ++j) ones[j] = 0x3F80;

  f32x4 o[2][4] = {};
  f32x4 lacc[2] = {};

  const int sr = t >> 3, sc = t & 7;
  ushort8 rk, rv;

#define STAGE_ATTN(buf)                                                      \
  {                                                                          \
    *(ushort8*)&Kl[buf][sr * 64 + ((sc ^ (sr & 7))) * 8] = rk;               \
    _Pragma("unroll") for (int h = 0; h < 2; ++h) {                          \
      int tw = 2 * sc + h;                                                   \
      int n4 = tw >> 2, gg = tw & 3;                                         \
      int chunk = ((n4 >> 1) << 2) + gg;                                     \
      int within = (n4 & 1) << 2;                                            \
      ushort4v hv = h ? __builtin_shufflevector(rv, rv, 4, 5, 6, 7)          \
                      : __builtin_shufflevector(rv, rv, 0, 1, 2, 3);         \
      *(ushort4v*)&Vl[buf][sr * 64 + ((chunk ^ (sr & 7))) * 8 + within] = hv;\
    }                                                                        \
  }

#define LOAD_NEXT(tile)                                                      \
  {                                                                          \
    rk = *(const ushort8*)&Kh[((tile) * 64 + sr) * 64 + sc * 8];             \
    rv = *(const ushort8*)&Vth[sr * 2048 + (tile) * 64 + sc * 8];            \
  }

#define COMPUTE_ATTN(cur)                                                    \
  {                                                                          \
    f32x4 s[2][2] = {};                                                      \
    __builtin_amdgcn_s_setprio(1);                                           \
    _Pragma("unroll") for (int kk = 0; kk < 2; ++kk) {                       \
      _Pragma("unroll") for (int n = 0; n < 2; ++n) {                        \
        ushort8 ak = *(const ushort8*)&Kl[cur][(kh * 32 + n * 16 + lr) * 64 +\
                                              (((kk * 4 + g) ^ (lr & 7))) * 8]; \
        _Pragma("unroll") for (int m = 0; m < 2; ++m)                        \
          s[n][m] = mfma16(ak, aq[m][kk], s[n][m]);                          \
      }                                                                      \
    }                                                                        \
    __builtin_amdgcn_s_setprio(0);                                           \
    float p[2][2][4];                                                        \
    _Pragma("unroll") for (int n = 0; n < 2; ++n)                            \
      _Pragma("unroll") for (int m = 0; m < 2; ++m)                          \
        _Pragma("unroll") for (int r = 0; r < 4; ++r)                        \
          p[n][m][r] = EXP2(s[n][m][r]);                                     \
    bf16x8 pa[2];                                                            \
    _Pragma("unroll") for (int m = 0; m < 2; ++m) {                          \
      f32x8 v = {p[0][m][0], p[0][m][1], p[0][m][2], p[0][m][3],             \
                 p[1][m][0], p[1][m][1], p[1][m][2], p[1][m][3]};            \
      pa[m] = __builtin_convertvector(v, bf16x8);                            \
    }                                                                        \
    __builtin_amdgcn_s_setprio(1);                                           \
    _Pragma("unroll") for (int m = 0; m < 2; ++m)                            \
      lacc[m] = mfma16b(pa[m], ones, lacc[m]);                               \
    _Pragma("unroll") for (int n = 0; n < 4; ++n) {                          \
      int d = n * 16 + lr;                                                   \
      ushort8 bv = *(const ushort8*)&Vl[cur][d * 64 +                        \
                                            (((kh * 4 + g) ^ (d & 7))) * 8]; \
      _Pragma("unroll") for (int m = 0; m < 2; ++m)                          \
        o[m][n] = mfma16b(pa[m], bv, o[m][n]);                               \
    }                                                                        \
    __builtin_amdgcn_s_setprio(0);                                           \
  }

  LOAD_NEXT(0)
  STAGE_ATTN(0)
  LOAD_NEXT(1)
  STAGE_ATTN(1)
  __syncthreads();

  for (int jj = 0; jj < 8; ++jj) {
    LOAD_NEXT(4 * jj + 2)
    COMPUTE_ATTN(0)
    STAGE_ATTN(2)
    LOAD_NEXT(4 * jj + 3)
    COMPUTE_ATTN(1)
    STAGE_ATTN(3)
    __syncthreads();
    if (jj < 7) LOAD_NEXT(4 * jj + 4)
    COMPUTE_ATTN(2)
    if (jj < 7) STAGE_ATTN(0)
    if (jj < 7) LOAD_NEXT(4 * jj + 5)
    COMPUTE_ATTN(3)
    if (jj < 7) STAGE_ATTN(1)
    __syncthreads();
  }

  __syncthreads();
  float* Of = (float*)&Kl[0][0];
  if (kh == 1) {
#pragma unroll
    for (int m = 0; m < 2; ++m)
#pragma unroll
      for (int n = 0; n < 4; ++n)
#pragma unroll
        for (int r = 0; r < 4; ++r)
          Of[(wq * 32 + m * 16 + g * 4 + r) * 64 + n * 16 + lr] = o[m][n][r];
  }
  __syncthreads();
  if (kh == 0) {
#pragma unroll
    for (int m = 0; m < 2; ++m)
#pragma unroll
      for (int n = 0; n < 4; ++n)
#pragma unroll
        for (int r = 0; r < 4; ++r)
          o[m][n][r] += Of[(wq * 32 + m * 16 + g * 4 + r) * 64 + n * 16 + lr];
  }
  __syncthreads();
  float* Lf = (float*)&Kl[0][0];
  if (kh == 1 && lr == 0) {
#pragma unroll
    for (int m = 0; m < 2; ++m)
#pragma unroll
      for (int r = 0; r < 4; ++r)
        Lf[wq * 32 + m * 16 + g * 4 + r] = lacc[m][r];
  }
  __syncthreads();
  if (kh == 0) {
    const int bb = bh >> 4, h = bh & 15;
#pragma unroll
    for (int m = 0; m < 2; ++m) {
      float inv[4];
#pragma unroll
      for (int r = 0; r < 4; ++r)
        inv[r] = 1.0f / (lacc[m][r] + Lf[wq * 32 + m * 16 + g * 4 + r]);
#pragma unroll
      for (int n = 0; n < 4; ++n)
#pragma unroll
        for (int r = 0; r < 4; ++r) {
          int q = qt * 128 + wq * 32 + m * 16 + g * 4 + r;
          AO[(size_t)(bb * 2048 + q) * 1024 + h * 64 + n * 16 + lr] =
              f2bf(o[m][n][r] * inv[r]);
        }
    }
  }
}

// ---------------- fallback kernels (small workspace) ----------------
__global__ __launch_bounds__(256) void gemm_qkv_f32(
    const float* __restrict__ Aq, const float* __restrict__ Ak, const float* __restrict__ Av,
    const float* __restrict__ Wq, const float* __restrict__ Wk, const float* __restrict__ Wv,
    const float* __restrict__ bq, const float* __restrict__ bk, const float* __restrict__ bv,
    unsigned short* __restrict__ Qb, unsigned short* __restrict__ Kb, unsigned short* __restrict__ Vtb)
{
  __shared__ __align__(16) unsigned short Al[128 * 32];
  __shared__ __align__(16) unsigned short Wl[128 * 32];
  const int z = blockIdx.z;
  const float* Ap = (z == 0) ? Aq : (z == 1) ? Ak : Av;
  const float* Wp = (z == 0) ? Wq : (z == 1) ? Wk : Wv;
  const float* bp = (z == 0) ? bq : (z == 1) ? bk : bv;

  const int t = threadIdx.x;
  const int l = t & 63, w = t >> 6;
  const int lr = l & 15, g = l >> 4;
  const int wm = (w >> 1) * 64, wn = (w & 1) * 64;
  const int bx = blockIdx.x, by = blockIdx.y;
  const int r0 = t >> 2, c0 = t & 3;

  f32x4 acc[4][4] = {};

  for (int k0 = 0; k0 < 1024; k0 += 32) {
    __syncthreads();
#pragma unroll
    for (int i = 0; i < 2; ++i) {
      int r = r0 + i * 64;
      int cs = c0 ^ ((r >> 1) & 3);
      *(ushort8*)&Al[r * 32 + cs * 8] = cvt8(Ap + (size_t)(by * 128 + r) * 1024 + k0 + c0 * 8);
      *(ushort8*)&Wl[r * 32 + cs * 8] = cvt8(Wp + (size_t)(bx * 128 + r) * 1024 + k0 + c0 * 8);
    }
    __syncthreads();
    ushort8 a[4], b[4];
#pragma unroll
    for (int m = 0; m < 4; ++m) {
      int r = wm + m * 16 + lr;
      a[m] = *(const ushort8*)&Al[r * 32 + (g ^ ((r >> 1) & 3)) * 8];
    }
#pragma unroll
    for (int n = 0; n < 4; ++n) {
      int r = wn + n * 16 + lr;
      b[n] = *(const ushort8*)&Wl[r * 32 + (g ^ ((r >> 1) & 3)) * 8];
    }
#pragma unroll
    for (int m = 0; m < 4; ++m)
#pragma unroll
      for (int n = 0; n < 4; ++n)
        acc[m][n] = mfma16(a[m], b[n], acc[m][n]);
  }

  float bias_n[4];
#pragma unroll
  for (int n = 0; n < 4; ++n) bias_n[n] = bp[bx * 128 + wn + n * 16 + lr];

  if (z < 2) {
    const float sc = (z == 0) ? QSCALE : 1.0f;
    unsigned short* Cp = z ? Kb : Qb;
#pragma unroll
    for (int m = 0; m < 4; ++m)
#pragma unroll
      for (int n = 0; n < 4; ++n)
#pragma unroll
        for (int r = 0; r < 4; ++r) {
          float v = (acc[m][n][r] + bias_n[n]) * sc;
          int gm = by * 128 + wm + m * 16 + g * 4 + r;
          int gn = bx * 128 + wn + n * 16 + lr;
          int bb = gm >> 11, s = gm & 2047;
          int h = gn >> 6, d = gn & 63;
          Cp[((size_t)((bb * 16 + h) * 2048 + s) << 6) + d] = f2bf(v);
        }
  } else {
#pragma unroll
    for (int m = 0; m < 4; ++m) {
      int gm0 = by * 128 + wm + m * 16 + g * 4;
      int bb = gm0 >> 11, s0 = gm0 & 2047;
#pragma unroll
      for (int n = 0; n < 4; ++n) {
        int gn = bx * 128 + wn + n * 16 + lr;
        int h = gn >> 6, d = gn & 63;
        ushort4v pk;
#pragma unroll
        for (int r = 0; r < 4; ++r) pk[r] = f2bf(acc[m][n][r] + bias_n[n]);
        *(ushort4v*)&Vtb[((size_t)((bb * 16 + h) * 64 + d) << 11) + s0] = pk;
      }
    }
  }
}

__global__ __launch_bounds__(256) void gemm_o_f32(
    const unsigned short* __restrict__ AO, const float* __restrict__ Wo,
    const float* __restrict__ bo, float* __restrict__ C)
{
  __shared__ __align__(16) unsigned short Al[128 * 32];
  __shared__ __align__(16) unsigned short Wl[64 * 32];
  const int t = threadIdx.x;
  const int l = t & 63, w = t >> 6;
  const int lr = l & 15, g = l >> 4;
  const int wm = w * 32;
  const int bx = blockIdx.x, by = blockIdx.y;
  const int r0 = t >> 2, c0 = t & 3;

  f32x4 acc[2][4] = {};

  for (int k0 = 0; k0 < 1024; k0 += 32) {
    __syncthreads();
#pragma unroll
    for (int i = 0; i < 2; ++i) {
      int r = r0 + i * 64;
      int cs = c0 ^ ((r >> 1) & 3);
      *(ushort8*)&Al[r * 32 + cs * 8] =
          *(const ushort8*)&AO[(size_t)(by * 128 + r) * 1024 + k0 + c0 * 8];
    }
    {
      int r = r0;
      int cs = c0 ^ ((r >> 1) & 3);
      *(ushort8*)&Wl[r * 32 + cs * 8] = cvt8(Wo + (size_t)(bx * 64 + r) * 1024 + k0 + c0 * 8);
    }
    __syncthreads();
    ushort8 a[2], b[4];
#pragma unroll
    for (int m = 0; m < 2; ++m) {
      int r = wm + m * 16 + lr;
      a[m] = *(const ushort8*)&Al[r * 32 + (g ^ ((r >> 1) & 3)) * 8];
    }
#pragma unroll
    for (int n = 0; n < 4; ++n) {
      int r = n * 16 + lr;
      b[n] = *(const ushort8*)&Wl[r * 32 + (g ^ ((r >> 1) & 3)) * 8];
    }
#pragma unroll
    for (int m = 0; m < 2; ++m)
#pragma unroll
      for (int n = 0; n < 4; ++n)
        acc[m][n] = mfma16(a[m], b[n], acc[m][n]);
  }

  float bias_n[4];
#pragma unroll
  for (int n = 0; n < 4; ++n) bias_n[n] = bo[bx * 64 + n * 16 + lr];

#pragma unroll
  for (int m = 0; m < 2; ++m)
#pragma unroll
    for (int n = 0; n < 4; ++n)
#pragma unroll
      for (int r = 0; r < 4; ++r) {
        int gm = by * 128 + wm + m * 16 + g * 4 + r;
        int gn = bx * 64 + n * 16 + lr;
        C[(size_t)gm * 1024 + gn] = acc[m][n][r] + bias_n[n];
      }
}

extern "C" void kernel_launch(void* const* d_in, const int* in_sizes, int n_in,
                              void* d_out, int out_size, void* d_ws, size_t ws_size,
                              hipStream_t stream) {
  (void)in_sizes; (void)n_in; (void)out_size;
  const float* querys = (const float*)d_in[0];
  const float* keys   = (const float*)d_in[1];
  const float* values = (const float*)d_in[2];
  const float* Wq = (const float*)d_in[3];
  const float* bq = (const float*)d_in[4];
  const float* Wk = (const float*)d_in[5];
  const float* bk = (const float*)d_in[6];
  const float* Wv = (const float*)d_in[7];
  const float* bv = (const float*)d_in[8];
  const float* Wo = (const float*)d_in[9];
  const float* bo = (const float*)d_in[10];

  const size_t need = (size_t)29360128 * 2;  // 58.7 MB
  if (ws_size >= need) {
    unsigned short* Wbf = (unsigned short*)d_ws;
    unsigned short* Qb  = Wbf + 4194304;
    unsigned short* Kb  = Qb + 4194304;
    unsigned short* Vtb = Kb + 4194304;
    unsigned short* Abf = Vtb + 4194304;
    unsigned short* AO  = Abf;

    cvt_f32_bf16<<<dim3(1024, 7), 256, 0, stream>>>(querys, keys, values, Wq, Wk, Wv, Wo,
                                                    Abf, Wbf);
    gemm_qkv_bf<<<dim3(8, 32, 3), 256, 0, stream>>>(Abf, Wbf, bq, bk, bv, Qb, Kb, Vtb);
    attn_fwd<<<dim3(16, 32), 512, 0, stream>>>(Qb, Kb, Vtb, AO);
    gemm_o_bf<<<dim3(16, 32), 256, 0, stream>>>(AO, Wbf + 3 * 1048576, bo, (float*)d_out);
  } else {
    unsigned short* Qb  = (unsigned short*)d_ws;
    unsigned short* Kb  = Qb + (size_t)4194304;
    unsigned short* Vtb = Kb + (size_t)4194304;
    unsigned short* AO  = Vtb + (size_t)4194304;

    gemm_qkv_f32<<<dim3(8, 32, 3), 256, 0, stream>>>(querys, keys, values, Wq, Wk, Wv,
                                                     bq, bk, bv, Qb, Kb, Vtb);
    attn_fwd<<<dim3(16, 32), 512, 0, stream>>>(Qb, Kb, Vtb, AO);
    gemm_o_f32<<<dim3(16, 32), 256, 0, stream>>>(AO, Wo, bo, (float*)d_out);
  }
}